// Round 3
// baseline (140.048 us; speedup 1.0000x reference)
//
#include <hip/hip_runtime.h>

// CostVolume: x,y fp32 [2,64,96,320]; GROUP=8 -> 16 (b,g) slabs x 8 channels.
// cost[bg,d,h,j] = sum_cc | xn[cc,j] - (j>=d ? yn[cc,j-d] : 0) |,
// xn/yn = per-pixel channel L2-normalized (norm + 1e-5).
// Output [2,8,49,96,320] fp32.
//
// R3: zero-divergence layout. Block = (bg, 3 consecutive rows), 240 threads
// = 3 rows x 80 quads; EVERY thread runs all 13 disparity groups (uniform
// loop bounds -> no divergent g-loop, unlike R2's t/80 split which made
// middle waves execute both dc ranges under partial masks). Per group g and
// channel, the y-window for 4 disparities x 4 columns is two ALIGNED quads
// (q-g-1, q-g): 2 ds_read_b128 per channel serve 16 outputs = 16 B/output
// LDS traffic. Stores are float4, d<49 guard is lane-uniform (scalar).
// Grid = 16 * 32 = 512 blocks = exactly 2/CU (balanced); LDS 60 KB/block.

#define HH    96
#define WW    320
#define HW    (HH * WW)      // 30720
#define NDISP 49
#define EPSN  1e-5f
#define ROWS  3
#define QR    (WW / 4)       // 80 quads per row
#define NT    (ROWS * QR)    // 240 threads
#define NC    (ROWS * WW)    // 960 columns per block

__global__ __launch_bounds__(NT) void cost_volume_kernel(
    const float* __restrict__ x, const float* __restrict__ y,
    float* __restrict__ out)
{
    __shared__ float xn_s[8][NC];
    __shared__ float yn_s[8][NC];

    const int t   = threadIdx.x;          // 0..239
    const int blk = blockIdx.x;           // 0..511
    const int hb  = blk % (HH / ROWS);    // 0..31
    const int bg  = blk / (HH / ROWS);    // 0..15
    const int h0  = hb * ROWS;

    // rows h0..h0+2 are contiguous: flat col c in [0,960) maps to
    // offset base + cc*HW + c for both inputs and the LDS arrays.
    const size_t base = (size_t)bg * 8 * HW + (size_t)h0 * WW;

    // ---- Phase A: thread t normalizes columns 4t..4t+3 ----
    {
        const int c = 4 * t;
        float4 xa[8], ya[8];
#pragma unroll
        for (int cc = 0; cc < 8; ++cc) {
            xa[cc] = *(const float4*)&x[base + (size_t)cc * HW + c];
            ya[cc] = *(const float4*)&y[base + (size_t)cc * HW + c];
        }
        float4 xs = make_float4(0.f, 0.f, 0.f, 0.f);
        float4 ys = make_float4(0.f, 0.f, 0.f, 0.f);
#pragma unroll
        for (int cc = 0; cc < 8; ++cc) {
            xs.x += xa[cc].x * xa[cc].x;  xs.y += xa[cc].y * xa[cc].y;
            xs.z += xa[cc].z * xa[cc].z;  xs.w += xa[cc].w * xa[cc].w;
            ys.x += ya[cc].x * ya[cc].x;  ys.y += ya[cc].y * ya[cc].y;
            ys.z += ya[cc].z * ya[cc].z;  ys.w += ya[cc].w * ya[cc].w;
        }
        const float4 xi = make_float4(1.f / (sqrtf(xs.x) + EPSN),
                                      1.f / (sqrtf(xs.y) + EPSN),
                                      1.f / (sqrtf(xs.z) + EPSN),
                                      1.f / (sqrtf(xs.w) + EPSN));
        const float4 yi = make_float4(1.f / (sqrtf(ys.x) + EPSN),
                                      1.f / (sqrtf(ys.y) + EPSN),
                                      1.f / (sqrtf(ys.z) + EPSN),
                                      1.f / (sqrtf(ys.w) + EPSN));
#pragma unroll
        for (int cc = 0; cc < 8; ++cc) {
            *(float4*)&xn_s[cc][c] = make_float4(xa[cc].x * xi.x, xa[cc].y * xi.y,
                                                 xa[cc].z * xi.z, xa[cc].w * xi.w);
            *(float4*)&yn_s[cc][c] = make_float4(ya[cc].x * yi.x, ya[cc].y * yi.y,
                                                 ya[cc].z * yi.z, ya[cc].w * yi.w);
        }
    }
    __syncthreads();

    // ---- Phase B: thread = (row r, quad q); ALL disparity groups ----
    const int q = t % QR;
    const int r = t / QR;
    const int Q = 4 * q;
    const int rowOff = r * WW;

    float4 xq[8];
#pragma unroll
    for (int cc = 0; cc < 8; ++cc)
        xq[cc] = *(const float4*)&xn_s[cc][rowOff + Q];

    // boundary cost (shifted y is zero pad): sum_cc |xn| per column
    float4 sA = make_float4(0.f, 0.f, 0.f, 0.f);
#pragma unroll
    for (int cc = 0; cc < 8; ++cc) {
        sA.x += fabsf(xq[cc].x);  sA.y += fabsf(xq[cc].y);
        sA.z += fabsf(xq[cc].z);  sA.w += fabsf(xq[cc].w);
    }

    float* outp = out + (size_t)bg * (NDISP * HW) + (size_t)(h0 + r) * WW + Q;

    for (int g = 0; g < 13; ++g) {      // d = 4g..4g+3 (g=12: only d=48 stored)
        int wq0 = q - g - 1; if (wq0 < 0) wq0 = 0;  // clamped reads feed only
        int wq1 = q - g;     if (wq1 < 0) wq1 = 0;  // boundary-overridden lanes
        const int a0 = rowOff + 4 * wq0;
        const int a1 = rowOff + 4 * wq1;

        float acc[4][4];   // [e][k]: disparity 4g+e, column Q+k
#pragma unroll
        for (int e = 0; e < 4; ++e)
#pragma unroll
            for (int k = 0; k < 4; ++k) acc[e][k] = 0.f;

#pragma unroll
        for (int cc = 0; cc < 8; ++cc) {
            const float4 wa = *(const float4*)&yn_s[cc][a0];
            const float4 wb = *(const float4*)&yn_s[cc][a1];
            const float win[8] = { wa.x, wa.y, wa.z, wa.w,
                                   wb.x, wb.y, wb.z, wb.w };
            const float4 xc = xq[cc];
#pragma unroll
            for (int e = 0; e < 4; ++e) {
                // column k at disparity d=4g+e uses yn col Q+k-d = win[k+4-e]
                acc[e][0] += fabsf(xc.x - win[4 - e]);
                acc[e][1] += fabsf(xc.y - win[5 - e]);
                acc[e][2] += fabsf(xc.z - win[6 - e]);
                acc[e][3] += fabsf(xc.w - win[7 - e]);
            }
        }

#pragma unroll
        for (int e = 0; e < 4; ++e) {
            const int d = 4 * g + e;
            if (d < NDISP) {                     // uniform -> scalar branch
                float4 rr;
                rr.x = (Q + 0 < d) ? sA.x : acc[e][0];
                rr.y = (Q + 1 < d) ? sA.y : acc[e][1];
                rr.z = (Q + 2 < d) ? sA.z : acc[e][2];
                rr.w = (Q + 3 < d) ? sA.w : acc[e][3];
                *(float4*)&outp[(size_t)d * HW] = rr;
            }
        }
    }
}

extern "C" void kernel_launch(void* const* d_in, const int* in_sizes, int n_in,
                              void* d_out, int out_size, void* d_ws, size_t ws_size,
                              hipStream_t stream) {
    const float* x = (const float*)d_in[0];
    const float* y = (const float*)d_in[1];
    float* out = (float*)d_out;
    dim3 grid(16 * (HH / ROWS));   // 512 blocks = 16 (b,g) x 32 row-triples
    dim3 block(NT);                // 240 threads = 3 rows x 80 quads
    cost_volume_kernel<<<grid, block, 0, stream>>>(x, y, out);
}

// Round 4
// 131.473 us; speedup vs baseline: 1.0652x; 1.0652x over previous
//
#include <hip/hip_runtime.h>

// CostVolume: x,y fp32 [2,64,96,320]; GROUP=8 -> 16 (b,g) slabs x 8 channels.
// cost[bg,d,h,j] = sum_cc | xn[cc,j] - (j>=d ? yn[cc,j-d] : 0) |,
// xn/yn per-pixel channel-L2-normalized (norm + 1e-5). Out [2,8,49,96,320] f32.
//
// R4 = R1 occupancy + R3 window trick + zero divergence:
//  - 1 row/block, 320 threads (5 waves), 1536 balanced blocks, LDS 20.5 KB
//    (xn+yn channel-major) -> ~20-30 waves/CU (R3's 61 KB gave only 7.5).
//  - Phase B: lane l of wave w serves quad q = w*16+(l&15), chunk dc = l>>4.
//    Each lane: 3 disparity groups g = 3*dc+gi (UNIFORM trip count -> no
//    divergent loop, unlike R2's t/80 split) + masked d=48 epilogue.
//  - Per (group, channel): 2 aligned ds_read_b128 (quads q-g-1, q-g) serve
//    4 disparities x 4 columns -> ~1 DS instr/output (R1 had 2), float4
//    stores (R1 had scalar). Window reads conflict-free: chunks consecutive
//    within each 16-lane quarter; xq reads broadcast across quarters.
//  - Left-pad boundary (j<d): clamped reads feed only sA-overridden lanes.

#define HH    96
#define WW    320
#define HW    (HH * WW)      // 30720
#define NDISP 49
#define EPSN  1e-5f

__global__ __launch_bounds__(WW, 4) void cost_volume_kernel(
    const float* __restrict__ x, const float* __restrict__ y,
    float* __restrict__ out)
{
    __shared__ float xn_s[8][WW];
    __shared__ float yn_s[8][WW];

    const int t   = threadIdx.x;     // 0..319
    const int blk = blockIdx.x;      // 0..1535
    const int h   = blk % HH;
    const int bg  = blk / HH;        // 0..15

    const size_t base = (size_t)bg * 8 * HW + (size_t)h * WW;

    // ---- Phase A: thread t normalizes column t, stages channel-major ----
    {
        float xv[8], yv[8];
        float xs = 0.f, ys = 0.f;
#pragma unroll
        for (int cc = 0; cc < 8; ++cc) {
            float xi = x[base + (size_t)cc * HW + t];
            float yi = y[base + (size_t)cc * HW + t];
            xv[cc] = xi; yv[cc] = yi;
            xs += xi * xi;
            ys += yi * yi;
        }
        const float xinv = 1.f / (sqrtf(xs) + EPSN);
        const float yinv = 1.f / (sqrtf(ys) + EPSN);
#pragma unroll
        for (int cc = 0; cc < 8; ++cc) {
            xn_s[cc][t] = xv[cc] * xinv;
            yn_s[cc][t] = yv[cc] * yinv;
        }
    }
    __syncthreads();

    // ---- Phase B: quad q = w*16 + (l&15), disparity chunk dc = l>>4 ----
    const int w  = t >> 6;           // wave 0..4
    const int l  = t & 63;
    const int q  = w * 16 + (l & 15);   // 0..79
    const int dc = l >> 4;              // 0..3
    const int Q  = 4 * q;

    // xn quad in registers (same-address broadcast across the 4 quarters)
    float4 xq[8];
#pragma unroll
    for (int cc = 0; cc < 8; ++cc)
        xq[cc] = *(const float4*)&xn_s[cc][Q];

    // boundary cost (shifted y is zero pad): sum_cc |xn| per column
    float4 sA = make_float4(0.f, 0.f, 0.f, 0.f);
#pragma unroll
    for (int cc = 0; cc < 8; ++cc) {
        sA.x += fabsf(xq[cc].x);  sA.y += fabsf(xq[cc].y);
        sA.z += fabsf(xq[cc].z);  sA.w += fabsf(xq[cc].w);
    }

    float* outp = out + (size_t)bg * (NDISP * HW) + (size_t)h * WW + Q;

#pragma unroll
    for (int gi = 0; gi < 3; ++gi) {
        const int g = 3 * dc + gi;       // 0..11; d = 4g..4g+3 (all <= 47)
        int wq0 = q - g - 1; if (wq0 < 0) wq0 = 0;  // clamped reads feed only
        int wq1 = q - g;     if (wq1 < 0) wq1 = 0;  // sA-overridden lanes
        const int a0 = 4 * wq0;
        const int a1 = 4 * wq1;

        float acc[4][4];   // [e][k]: disparity 4g+e, column Q+k
#pragma unroll
        for (int e = 0; e < 4; ++e)
#pragma unroll
            for (int k = 0; k < 4; ++k) acc[e][k] = 0.f;

#pragma unroll
        for (int cc = 0; cc < 8; ++cc) {
            const float4 wa = *(const float4*)&yn_s[cc][a0];
            const float4 wb = *(const float4*)&yn_s[cc][a1];
            const float win[8] = { wa.x, wa.y, wa.z, wa.w,
                                   wb.x, wb.y, wb.z, wb.w };
            const float4 xc = xq[cc];
#pragma unroll
            for (int e = 0; e < 4; ++e) {
                // column k at disparity d=4g+e uses yn col Q+k-d = win[k+4-e]
                acc[e][0] += fabsf(xc.x - win[4 - e]);
                acc[e][1] += fabsf(xc.y - win[5 - e]);
                acc[e][2] += fabsf(xc.z - win[6 - e]);
                acc[e][3] += fabsf(xc.w - win[7 - e]);
            }
        }

#pragma unroll
        for (int e = 0; e < 4; ++e) {
            const int d = 4 * g + e;
            float4 rr;
            rr.x = (Q + 0 < d) ? sA.x : acc[e][0];
            rr.y = (Q + 1 < d) ? sA.y : acc[e][1];
            rr.z = (Q + 2 < d) ? sA.z : acc[e][2];
            rr.w = (Q + 3 < d) ? sA.w : acc[e][3];
            *(float4*)&outp[(size_t)d * HW] = rr;
        }
    }

    // ---- Epilogue: d = 48 (computed by all quarters, stored by dc==0) ----
    {
        int wq = q - 12; if (wq < 0) wq = 0;
        const int a = 4 * wq;
        float4 acc = make_float4(0.f, 0.f, 0.f, 0.f);
#pragma unroll
        for (int cc = 0; cc < 8; ++cc) {
            const float4 wv = *(const float4*)&yn_s[cc][a];
            acc.x += fabsf(xq[cc].x - wv.x);
            acc.y += fabsf(xq[cc].y - wv.y);
            acc.z += fabsf(xq[cc].z - wv.z);
            acc.w += fabsf(xq[cc].w - wv.w);
        }
        float4 rr;
        rr.x = (Q + 0 < 48) ? sA.x : acc.x;
        rr.y = (Q + 1 < 48) ? sA.y : acc.y;
        rr.z = (Q + 2 < 48) ? sA.z : acc.z;
        rr.w = (Q + 3 < 48) ? sA.w : acc.w;
        if (dc == 0)
            *(float4*)&outp[(size_t)48 * HW] = rr;
    }
}

extern "C" void kernel_launch(void* const* d_in, const int* in_sizes, int n_in,
                              void* d_out, int out_size, void* d_ws, size_t ws_size,
                              hipStream_t stream) {
    const float* x = (const float*)d_in[0];
    const float* y = (const float*)d_in[1];
    float* out = (float*)d_out;
    dim3 grid(16 * HH);   // 1536 blocks: one per (b,g,h) row -> 6/CU balanced
    dim3 block(WW);       // 320 threads = 5 waves
    cost_volume_kernel<<<grid, block, 0, stream>>>(x, y, out);
}